// Round 6
// baseline (494.631 us; speedup 1.0000x reference)
//
#include <hip/hip_runtime.h>
#include <hip/hip_bf16.h>

#define DDIM 256
#define NROWS 8192
#define LOG2E5 7.2134752044448170f   // 5 / ln(2): exp(5x) = exp2(LOG2E5 * x)

typedef __attribute__((ext_vector_type(8)))  __bf16 bf16x8;
typedef __attribute__((ext_vector_type(16))) float  floatx16;

// Fragment-order layout for mfma_32x32x16_bf16 operands (A and B identical:
// both are row-major matrices feeding A*B^T):
//   32-row group R (rows 32R + (lane&31)), k-granule G (k = 16G + (lane>>5)*8 + j)
//   8 bf16 at: X + ((R*16 + G)*64 + lane)*8
// One wave fragment load = contiguous 1 KB global_load_dwordx4.

// Kernel 1: one 32-row group per block (256 blocks). L2-normalize U,P rows,
// pos_sim, zero rowsum/out/counter, write Af/Pf in fragment order.
__global__ __launch_bounds__(256) void normalize_repack(
    const float* __restrict__ U, const float* __restrict__ P,
    unsigned short* __restrict__ Af, unsigned short* __restrict__ Pf,
    float* __restrict__ possim, float* __restrict__ rowsum,
    float* __restrict__ out, int* __restrict__ counter)
{
    __shared__ unsigned short Ut[32 * 264];
    __shared__ unsigned short Pt[32 * 264];
    const int tid = threadIdx.x;
    const int R   = blockIdx.x;            // 0..255
    const int r32 = tid >> 3;              // row in group, 0..31
    const int c   = tid & 7;               // 8 threads per row
    const int row = R * 32 + r32;

    if (R == 0 && tid == 0) { out[0] = 0.0f; counter[0] = 0; }
    if (c == 0) rowsum[row] = 0.0f;

    float4 u4[8], p4[8];
    float su = 0.0f, sp = 0.0f, up = 0.0f;
    #pragma unroll
    for (int j = 0; j < 8; ++j) {
        const size_t base = (size_t)row * DDIM + c * 32 + j * 4;
        u4[j] = *(const float4*)(U + base);
        p4[j] = *(const float4*)(P + base);
        su += u4[j].x*u4[j].x + u4[j].y*u4[j].y + u4[j].z*u4[j].z + u4[j].w*u4[j].w;
        sp += p4[j].x*p4[j].x + p4[j].y*p4[j].y + p4[j].z*p4[j].z + p4[j].w*p4[j].w;
        up += u4[j].x*p4[j].x + u4[j].y*p4[j].y + u4[j].z*p4[j].z + u4[j].w*p4[j].w;
    }
    #pragma unroll
    for (int d = 1; d < 8; d <<= 1) {      // reduce across the row's 8 lanes
        su += __shfl_xor(su, d);
        sp += __shfl_xor(sp, d);
        up += __shfl_xor(up, d);
    }
    const float iu = rsqrtf(fmaxf(su, 1e-24f));
    const float ip = rsqrtf(fmaxf(sp, 1e-24f));
    if (c == 0) possim[row] = up * iu * ip;

    #pragma unroll
    for (int j = 0; j < 8; ++j) {
        union { ushort4 s4; __hip_bfloat16 h[4]; } cu, cp;
        cu.h[0] = __float2bfloat16(u4[j].x * iu); cu.h[1] = __float2bfloat16(u4[j].y * iu);
        cu.h[2] = __float2bfloat16(u4[j].z * iu); cu.h[3] = __float2bfloat16(u4[j].w * iu);
        cp.h[0] = __float2bfloat16(p4[j].x * ip); cp.h[1] = __float2bfloat16(p4[j].y * ip);
        cp.h[2] = __float2bfloat16(p4[j].z * ip); cp.h[3] = __float2bfloat16(p4[j].w * ip);
        *(ushort4*)&Ut[r32 * 264 + c * 32 + j * 4] = cu.s4;
        *(ushort4*)&Pt[r32 * 264 + c * 32 + j * 4] = cp.s4;
    }
    __syncthreads();

    // Repack: wave wv writes granules G = 4wv..4wv+3 for both matrices.
    const int lane = tid & 63;
    const int wv   = tid >> 6;
    const int m  = lane & 31;
    const int kh = lane >> 5;
    #pragma unroll
    for (int g = 0; g < 4; ++g) {
        const int G = wv * 4 + g;
        const bf16x8 ua = *(const bf16x8*)&Ut[m * 264 + G * 16 + kh * 8];
        const bf16x8 pa = *(const bf16x8*)&Pt[m * 264 + G * 16 + kh * 8];
        const size_t o = ((size_t)(R * 16 + G) * 64 + lane) * 8;
        *(bf16x8*)(Af + o) = ua;
        *(bf16x8*)(Pf + o) = pa;
    }
}

// Kernel 2: 128x128 tile per block, 4096 blocks, NO LDS, no barriers in the
// K-loop. 4 waves (2x2), wave tile 64x64 via 2x2 of mfma_32x32x16_bf16
// (acc = 4x16 VGPR, fragments 4 VGPR each -> small state, 4 waves/SIMD).
// Per k-step: 4 contiguous 1 KB fragment loads + 4 MFMA, register
// double-buffered; waves free-run with compiler vmcnt(N) scheduling.
// XCD swizzle: blockIdx&7 = XCD; each XCD owns an 8-col-tile band of B
// (8*128 cols x 512 B = 512 KB, L2-resident).
__global__ __launch_bounds__(256, 4) void sim_exp_rowsum(
    const unsigned short* __restrict__ Af,
    const unsigned short* __restrict__ Pf,
    float* __restrict__ rowsum,
    const float* __restrict__ possim,
    int* __restrict__ counter,
    float* __restrict__ out)
{
    __shared__ float ws4[4];
    __shared__ int ticket_s;
    const int tid  = threadIdx.x;
    const int lane = tid & 63;
    const int wv   = tid >> 6;
    const int wr   = wv >> 1, wc = wv & 1;

    const int xcd = blockIdx.x & 7;
    const int lin = blockIdx.x >> 3;       // 0..511
    const int CX  = xcd * 8 + (lin & 7);   // col tile 0..63 (XCD-local band)
    const int RY  = lin >> 3;              // row tile 0..63

    // fragment base offsets (elements)
    const size_t abase = ((size_t)(RY * 4 + wr * 2) * 16 * 64 + lane) * 8;
    const size_t bbase = ((size_t)(CX * 4 + wc * 2) * 16 * 64 + lane) * 8;
    // t/u stride = 16*64*8 = 8192 elems; ks stride = 64*8 = 512 elems

    floatx16 acc[2][2];
    #pragma unroll
    for (int t = 0; t < 2; ++t)
        #pragma unroll
        for (int u = 0; u < 2; ++u)
            #pragma unroll
            for (int r = 0; r < 16; ++r)
                acc[t][u][r] = 0.0f;

    bf16x8 a0 = *(const bf16x8*)(Af + abase);
    bf16x8 a1 = *(const bf16x8*)(Af + abase + 8192);
    bf16x8 b0 = *(const bf16x8*)(Pf + bbase);
    bf16x8 b1 = *(const bf16x8*)(Pf + bbase + 8192);

    #pragma unroll
    for (int ks = 0; ks < 16; ++ks) {
        bf16x8 a0n, a1n, b0n, b1n;
        if (ks < 15) {
            const size_t ko = (size_t)(ks + 1) * 512;
            a0n = *(const bf16x8*)(Af + abase + ko);
            a1n = *(const bf16x8*)(Af + abase + 8192 + ko);
            b0n = *(const bf16x8*)(Pf + bbase + ko);
            b1n = *(const bf16x8*)(Pf + bbase + 8192 + ko);
        }
        acc[0][0] = __builtin_amdgcn_mfma_f32_32x32x16_bf16(a0, b0, acc[0][0], 0, 0, 0);
        acc[0][1] = __builtin_amdgcn_mfma_f32_32x32x16_bf16(a0, b1, acc[0][1], 0, 0, 0);
        acc[1][0] = __builtin_amdgcn_mfma_f32_32x32x16_bf16(a1, b0, acc[1][0], 0, 0, 0);
        acc[1][1] = __builtin_amdgcn_mfma_f32_32x32x16_bf16(a1, b1, acc[1][1], 0, 0, 0);
        if (ks < 15) { a0 = a0n; a1 = a1n; b0 = b0n; b1 = b1n; }
    }

    // Epilogue. C/D of 32x32: col = lane&31, row = (reg&3) + 8*(reg>>2) + 4*(lane>>5).
    // Sum exp2 over both u tiles, then reduce the 32 column lanes (xor<=16
    // stays within each 32-lane half; halves hold different rows).
    #pragma unroll
    for (int t = 0; t < 2; ++t) {
        #pragma unroll
        for (int reg = 0; reg < 16; ++reg) {
            float s = exp2f(LOG2E5 * acc[t][0][reg])
                    + exp2f(LOG2E5 * acc[t][1][reg]);
            s += __shfl_xor(s, 1);
            s += __shfl_xor(s, 2);
            s += __shfl_xor(s, 4);
            s += __shfl_xor(s, 8);
            s += __shfl_xor(s, 16);
            if ((lane & 31) == 0) {
                const int row = RY * 128 + wr * 64 + t * 32
                              + (reg & 3) + 8 * (reg >> 2) + 4 * (lane >> 5);
                atomicAdd(&rowsum[row], s);
            }
        }
    }

    // Fused finalize: last block computes loss = mean(log(rowsum) - 5*possim).
    __threadfence();
    __syncthreads();
    if (tid == 0)
        ticket_s = __hip_atomic_fetch_add(counter, 1, __ATOMIC_ACQ_REL,
                                          __HIP_MEMORY_SCOPE_AGENT);
    __syncthreads();
    if (ticket_s == 4095) {
        float part = 0.0f;
        for (int idx = tid; idx < NROWS; idx += 256) {
            const float rs = __hip_atomic_load(&rowsum[idx], __ATOMIC_RELAXED,
                                               __HIP_MEMORY_SCOPE_AGENT);
            part += __logf(rs) - 5.0f * possim[idx];
        }
        #pragma unroll
        for (int d = 1; d < 64; d <<= 1) part += __shfl_xor(part, d);
        if (lane == 0) ws4[wv] = part;
        __syncthreads();
        if (tid == 0)
            out[0] = (ws4[0] + ws4[1] + ws4[2] + ws4[3]) * (1.0f / (float)NROWS);
    }
}

extern "C" void kernel_launch(void* const* d_in, const int* in_sizes, int n_in,
                              void* d_out, int out_size, void* d_ws, size_t ws_size,
                              hipStream_t stream) {
    const float* U = (const float*)d_in[0];
    const float* P = (const float*)d_in[1];
    float* out = (float*)d_out;
    char* ws = (char*)d_ws;
    // ws: Af bf16 frag-order (4 MB) | Pf (4 MB) | rowsum (32 KB) | possim (32 KB) | counter
    unsigned short* Af = (unsigned short*)ws;
    unsigned short* Pf = (unsigned short*)(ws + 4194304);
    float* rowsum = (float*)(ws + 8388608);
    float* possim = (float*)(ws + 8388608 + 32768);
    int* counter  = (int*)(ws + 8388608 + 65536);

    normalize_repack<<<NROWS / 32, 256, 0, stream>>>(U, P, Af, Pf, possim, rowsum,
                                                     out, counter);
    sim_exp_rowsum<<<4096, 256, 0, stream>>>(Af, Pf, rowsum, possim, counter, out);
}

// Round 7
// 187.332 us; speedup vs baseline: 2.6404x; 2.6404x over previous
//
#include <hip/hip_runtime.h>
#include <hip/hip_bf16.h>
#include <stdint.h>

#define DDIM 256
#define NROWS 8192
#define LOG2E5 7.2134752044448170f   // 5 / ln(2): exp(5x) = exp2(LOG2E5 * x)

typedef __attribute__((ext_vector_type(4))) float floatx4;

// async global->LDS, 16B per lane; LDS dest = wave-uniform base + lane*16.
__device__ __forceinline__ void async16(const void* g, void* l) {
    __builtin_amdgcn_global_load_lds(
        (const __attribute__((address_space(1))) unsigned int*)g,
        (__attribute__((address_space(3))) unsigned int*)l,
        16, 0, 0);
}

// Kernel 1: L2-normalize rows of U,P -> fp8 e4m3 row-major (256 B/row),
// pos_sim in fp32 (exact), zero rowsum/out/counter. One wave per row.
__global__ __launch_bounds__(256) void normalize_fp8(
    const float* __restrict__ U, const float* __restrict__ P,
    unsigned char* __restrict__ Uq, unsigned char* __restrict__ Pq,
    float* __restrict__ possim, float* __restrict__ rowsum,
    float* __restrict__ out, int* __restrict__ counter)
{
    if (blockIdx.x == 0 && threadIdx.x == 0) { out[0] = 0.0f; counter[0] = 0; }
    const int lane = threadIdx.x & 63;
    const int row  = blockIdx.x * 4 + (threadIdx.x >> 6);
    const size_t base = (size_t)row * DDIM + lane * 4;
    const float4 u4 = *(const float4*)(U + base);
    const float4 p4 = *(const float4*)(P + base);
    float su = u4.x*u4.x + u4.y*u4.y + u4.z*u4.z + u4.w*u4.w;
    float sp = p4.x*p4.x + p4.y*p4.y + p4.z*p4.z + p4.w*p4.w;
    float up = u4.x*p4.x + u4.y*p4.y + u4.z*p4.z + u4.w*p4.w;
    #pragma unroll
    for (int d = 1; d < 64; d <<= 1) {
        su += __shfl_xor(su, d);
        sp += __shfl_xor(sp, d);
        up += __shfl_xor(up, d);
    }
    const float iu = rsqrtf(fmaxf(su, 1e-24f));
    const float ip = rsqrtf(fmaxf(sp, 1e-24f));
    if (lane == 0) {
        possim[row] = up * iu * ip;
        rowsum[row] = 0.0f;
    }
    // pack 4 normalized floats -> 4 fp8 bytes (v_cvt_pk_fp8_f32, OCP on gfx950)
    int pu = __builtin_amdgcn_cvt_pk_fp8_f32(u4.x * iu, u4.y * iu, 0, false);
    pu     = __builtin_amdgcn_cvt_pk_fp8_f32(u4.z * iu, u4.w * iu, pu, true);
    int pp = __builtin_amdgcn_cvt_pk_fp8_f32(p4.x * ip, p4.y * ip, 0, false);
    pp     = __builtin_amdgcn_cvt_pk_fp8_f32(p4.z * ip, p4.w * ip, pp, true);
    ((int*)Uq)[(size_t)row * 64 + lane] = pu;
    ((int*)Pq)[(size_t)row * 64 + lane] = pp;
}

// Kernel 2: fp8 GEMM + exp-rowsum + fused finalize.
// 1024 blocks = 128 stripes x 8 octants (oct = blockIdx&7 -> round-robin XCD:
// each XCD streams ONE 1024-col B octant = 256 KB fp8, L2-resident).
// Block: 64 rows x 1024 cols; 4 waves 2x2; wave-tile 32x32 via 2x2 of
// mfma_f32_16x16x32_fp8_fp8 (A/B frag = 8 B/lane, layout-identical to bf16).
// LDS 48 KB (A 16 KB staged once + B 2 x 16 KB dbuf) -> 3 blocks/CU, so other
// blocks' compute covers each block's barrier drains; B[i+1] is issued right
// after the barrier and lands during a full compute phase.
// LDS swizzle: 16 B granule P at row r holds logical granule P^(r&7):
// staging stays 16 B-contiguous per lane; ds_read_b64 frag reads are <=2-way
// bank-aliased (free). A-frags register-resident (16 x 8 B = 32 VGPR).
__global__ __launch_bounds__(256, 3) void sim_exp_rowsum(
    const unsigned char* __restrict__ Uq,
    const unsigned char* __restrict__ Pq,
    float* __restrict__ rowsum,
    const float* __restrict__ possim,
    int* __restrict__ counter,
    float* __restrict__ out)
{
    __shared__ __align__(16) unsigned char As[64 * 256];      // 16 KB
    __shared__ __align__(16) unsigned char Bs[2][64 * 256];   // 32 KB
    __shared__ float ws4[4];
    __shared__ int ticket_s;

    const int tid  = threadIdx.x;
    const int lane = tid & 63;
    const int wv   = tid >> 6;
    const int wr   = wv >> 1, wc = wv & 1;
    const int m = lane & 15, q = lane >> 4;

    const int oct    = blockIdx.x & 7;
    const int stripe = blockIdx.x >> 3;    // 0..127

    const int r_off = lane >> 4;           // staging: 4 rows per async16
    const int Pg    = lane & 15;           // physical 16 B granule

    const unsigned char* Ag = Uq + (size_t)stripe * 64 * DDIM;
    const unsigned char* Bg = Pq + (size_t)oct * 1024 * DDIM;

    // ---- stage A stripe (64 rows) + B tile 0 ----
    #pragma unroll
    for (int j = 0; j < 4; ++j) {
        const int r0 = wv * 16 + j * 4;
        const int r  = r0 + r_off;
        async16(Ag + (size_t)r * DDIM + ((Pg ^ (r & 7)) * 16), &As[r0 * 256]);
    }
    #pragma unroll
    for (int j = 0; j < 4; ++j) {
        const int r0 = wv * 16 + j * 4;
        const int r  = r0 + r_off;
        async16(Bg + (size_t)r * DDIM + ((Pg ^ (r & 7)) * 16), &Bs[0][r0 * 256]);
    }
    __syncthreads();   // drain A + B0

    // ---- A fragments -> registers (2 row-tiles x 8 k-steps, 8 B each) ----
    int64_t afr[2][8];
    #pragma unroll
    for (int t = 0; t < 2; ++t) {
        const int arow = wr * 32 + t * 16 + m;
        #pragma unroll
        for (int ks = 0; ks < 8; ++ks) {
            const int G = 2 * ks + (q >> 1);
            afr[t][ks] = *(const int64_t*)&As[arow * 256
                             + ((G ^ (m & 7)) * 16) + (q & 1) * 8];
        }
    }

    float rowpart[2][4];
    #pragma unroll
    for (int t = 0; t < 2; ++t)
        #pragma unroll
        for (int r = 0; r < 4; ++r)
            rowpart[t][r] = 0.0f;

    // ---- main loop: 16 B-tiles of 64 cols ----
    for (int i = 0; i < 16; ++i) {
        if (i > 0) __syncthreads();        // drain B[i] (issued in iter i-1)
        if (i < 15) {
            const unsigned char* Bt = Bg + (size_t)(i + 1) * 64 * DDIM;
            unsigned char* dst = Bs[(i + 1) & 1];
            #pragma unroll
            for (int j = 0; j < 4; ++j) {
                const int r0 = wv * 16 + j * 4;
                const int r  = r0 + r_off;
                async16(Bt + (size_t)r * DDIM + ((Pg ^ (r & 7)) * 16),
                        dst + r0 * 256);
            }
        }
        const unsigned char* Bp = Bs[i & 1];

        floatx4 acc[2][2];
        #pragma unroll
        for (int t = 0; t < 2; ++t) {
            acc[t][0] = {0.0f, 0.0f, 0.0f, 0.0f};
            acc[t][1] = {0.0f, 0.0f, 0.0f, 0.0f};
        }
        #pragma unroll
        for (int ks = 0; ks < 8; ++ks) {
            const int G = 2 * ks + (q >> 1);
            const int gofs = ((G ^ (m & 7)) * 16) + (q & 1) * 8;
            const int brow0 = wc * 32 + m;
            const int64_t b0 = *(const int64_t*)&Bp[brow0 * 256 + gofs];
            const int64_t b1 = *(const int64_t*)&Bp[(brow0 + 16) * 256 + gofs];
            #pragma unroll
            for (int t = 0; t < 2; ++t) {
                acc[t][0] = __builtin_amdgcn_mfma_f32_16x16x32_fp8_fp8(
                    afr[t][ks], b0, acc[t][0], 0, 0, 0);
                acc[t][1] = __builtin_amdgcn_mfma_f32_16x16x32_fp8_fp8(
                    afr[t][ks], b1, acc[t][1], 0, 0, 0);
            }
        }
        // exp(5*sim) accumulated per-lane; C/D: col = m, row = q*4 + r (+t*16)
        #pragma unroll
        for (int t = 0; t < 2; ++t)
            #pragma unroll
            for (int r = 0; r < 4; ++r)
                rowpart[t][r] += exp2f(LOG2E5 * acc[t][0][r])
                               + exp2f(LOG2E5 * acc[t][1][r]);
    }

    // ---- reduce 16 column-lanes, one atomic per row per wave ----
    #pragma unroll
    for (int t = 0; t < 2; ++t) {
        #pragma unroll
        for (int r = 0; r < 4; ++r) {
            float s = rowpart[t][r];
            s += __shfl_xor(s, 1);
            s += __shfl_xor(s, 2);
            s += __shfl_xor(s, 4);
            s += __shfl_xor(s, 8);
            if (m == 0) {
                const int grow = stripe * 64 + wr * 32 + t * 16 + q * 4 + r;
                atomicAdd(&rowsum[grow], s);
            }
        }
    }

    // ---- fused finalize: last block computes mean(log(rowsum) - 5*possim) ----
    __threadfence();
    __syncthreads();
    if (tid == 0)
        ticket_s = __hip_atomic_fetch_add(counter, 1, __ATOMIC_ACQ_REL,
                                          __HIP_MEMORY_SCOPE_AGENT);
    __syncthreads();
    if (ticket_s == 1023) {
        float part = 0.0f;
        for (int idx = tid; idx < NROWS; idx += 256) {
            const float rs = __hip_atomic_load(&rowsum[idx], __ATOMIC_RELAXED,
                                               __HIP_MEMORY_SCOPE_AGENT);
            part += __logf(rs) - 5.0f * possim[idx];
        }
        #pragma unroll
        for (int d = 1; d < 64; d <<= 1) part += __shfl_xor(part, d);
        if (lane == 0) ws4[wv] = part;
        __syncthreads();
        if (tid == 0)
            out[0] = (ws4[0] + ws4[1] + ws4[2] + ws4[3]) * (1.0f / (float)NROWS);
    }
}

extern "C" void kernel_launch(void* const* d_in, const int* in_sizes, int n_in,
                              void* d_out, int out_size, void* d_ws, size_t ws_size,
                              hipStream_t stream) {
    const float* U = (const float*)d_in[0];
    const float* P = (const float*)d_in[1];
    float* out = (float*)d_out;
    char* ws = (char*)d_ws;
    // ws: Uq fp8 (2 MB) | Pq fp8 (2 MB) | rowsum (32 KB) | possim (32 KB) | counter
    unsigned char* Uq = (unsigned char*)ws;
    unsigned char* Pq = (unsigned char*)(ws + 2097152);
    float* rowsum = (float*)(ws + 4194304);
    float* possim = (float*)(ws + 4194304 + 32768);
    int* counter  = (int*)(ws + 4194304 + 65536);

    normalize_fp8<<<NROWS / 4, 256, 0, stream>>>(U, P, Uq, Pq, possim, rowsum,
                                                 out, counter);
    sim_exp_rowsum<<<1024, 256, 0, stream>>>(Uq, Pq, rowsum, possim, counter, out);
}